// Round 20
// baseline (26.786 us; speedup 1.0000x reference)
//
#include <hip/hip_runtime.h>
#include <math.h>

#define N_NODES 10000
#define N_REL   500
#define H       128
#define L       128

#define TN    20     // n-tile: 500 * 20 = 10000 exactly
#define NBLK  500    // grid of k_main (2 blocks/CU, 8 waves each -> 4 waves/SIMD)
#define PSTR  512    // psum row stride

__device__ __forceinline__ void gload16(const float* g, float* l) {
    __builtin_amdgcn_global_load_lds((const __attribute__((address_space(1))) void*)g,
                                     (__attribute__((address_space(3))) void*)l, 16, 0, 0);
}

// --- K1: 512-thread version of r19 (best: 25.75 us) --------------------------
// 8 waves split h into 16-wide segments; lane tile 8l x 5n unchanged
// (13 ds_read_b128 per 40 acc per quad -- same per-FLOP mix as r19, 2x TLP).
// LDS content swizzle: stored[row][c] = src[row][c ^ ((row&7)<<2)]
// e raw in LDS; inverse norm folded into fma (r19-validated).
// Two-stage merge through the 43 KB aliased buffer.
__global__ __launch_bounds__(512, 4) void k_main(const float* __restrict__ node,
                                                 const float* __restrict__ rel,
                                                 const int* __restrict__ eidx,
                                                 const int* __restrict__ ridx,
                                                 float* __restrict__ out,
                                                 float* __restrict__ psum) {
    __shared__ union {
        float qs[L * H];            // 64 KB  (build + main-loop phase)
        float red[4][128][21];      // 43 KB  (merge phase, aliases qs)
    } u;
    __shared__ float es[TN * H];    // 10 KB
    __shared__ float invs[TN];

    const int tid  = threadIdx.x;
    const int w    = tid >> 6;          // wave id 0..7 = h-segment (16 h each)
    const int lane = tid & 63;
    const int grp  = lane >> 2;         // 0..15
    const int nl   = lane & 3;          // 0..3
    const int nb   = blockIdx.x * TN;   // exact, no bounds checks

    // ---- A1: issue es staging DMA (overlaps the query build below) ----
    {
        const int c0   = (lane & 31) << 2;
        const int roff = lane >> 5;
        #pragma unroll
        for (int k = 0; k < 10; ++k) {
            if ((k & 7) == w) {         // waves 0,1 take two pairs; 2..7 one
                int r = k * 2;
                int row = r + roff;
                int g = (row & 7) << 2;
                gload16(node + (size_t)(nb + row) * H + (c0 ^ g), &es[r * H]);
            }
        }
    }

    // ---- A2: build all 128 query rows into qs (redundant per block) ----
    #pragma unroll
    for (int it = 0; it < 2; ++it) {
        int row = it * 64 + (tid >> 3);
        int seg = tid & 7;
        int ei = eidx[row], ri = ridx[row];
        const float4* pe = reinterpret_cast<const float4*>(node + (size_t)ei * H + seg * 16);
        const float4* pr = reinterpret_cast<const float4*>(rel  + (size_t)ri * H + seg * 16);
        float4 ev[4], rv[4];
        #pragma unroll
        for (int u2 = 0; u2 < 4; ++u2) { ev[u2] = pe[u2]; rv[u2] = pr[u2]; }
        float se = 0.f, sr = 0.f;
        #pragma unroll
        for (int u2 = 0; u2 < 4; ++u2) {
            se += ev[u2].x * ev[u2].x + ev[u2].y * ev[u2].y
                + ev[u2].z * ev[u2].z + ev[u2].w * ev[u2].w;
            sr += rv[u2].x * rv[u2].x + rv[u2].y * rv[u2].y
                + rv[u2].z * rv[u2].z + rv[u2].w * rv[u2].w;
        }
        se += __shfl_xor(se, 1, 64); se += __shfl_xor(se, 2, 64); se += __shfl_xor(se, 4, 64);
        sr += __shfl_xor(sr, 1, 64); sr += __shfl_xor(sr, 2, 64); sr += __shfl_xor(sr, 4, 64);
        float inve = 1.0f / fmaxf(sqrtf(se), 1e-12f);
        float invr = 1.0f / fmaxf(sqrtf(sr), 1e-12f);
        int g = (row & 7) << 2;
        float* dst = u.qs + row * H;
        #pragma unroll
        for (int u2 = 0; u2 < 4; ++u2) {
            float4 q;
            q.x = ev[u2].x * inve + rv[u2].x * invr;
            q.y = ev[u2].y * inve + rv[u2].y * invr;
            q.z = ev[u2].z * inve + rv[u2].z * invr;
            q.w = ev[u2].w * inve + rv[u2].w * invr;
            int c = (seg * 16 + u2 * 4) ^ g;        // 16B-aligned, swizzled
            *reinterpret_cast<float4*>(dst + c) = q;
        }
    }
    __syncthreads();   // drains es DMA (vmcnt) + qs LDS writes

    // ---- A3: inverse norms of the 20 es rows (swizzle-invariant) ----
    if (tid < 8 * TN) {
        int row = tid >> 3, seg = tid & 7;
        const float4* p = reinterpret_cast<const float4*>(es + row * H + seg * 16);
        float ss = 0.f;
        #pragma unroll
        for (int u2 = 0; u2 < 4; ++u2) {
            float4 v = p[u2];
            ss += v.x * v.x + v.y * v.y + v.z * v.z + v.w * v.w;
        }
        #pragma unroll
        for (int m = 1; m < 8; m <<= 1) ss += __shfl_xor(ss, m, 64);
        if (seg == 0) invs[row] = 1.0f / fmaxf(sqrtf(ss), 1e-12f);
    }
    __syncthreads();

    // ---- B: main loop, 4 h-quads in this wave's 16-h segment ----
    const int hs = w * 16;
    const int gq = (grp & 7) << 2;
    int gej[5];
    float sj[5];
    #pragma unroll
    for (int j = 0; j < 5; ++j) {
        gej[j] = ((nl + 4 * j) & 7) << 2;
        sj[j]  = invs[nl + 4 * j];
    }

    float acc[8][5] = {};

    #pragma unroll
    for (int hc = 0; hc < 4; ++hc) {
        const int h = hs + (hc << 2);
        float4 qf[8], ef[5];
        #pragma unroll
        for (int i = 0; i < 8; ++i)
            qf[i] = *reinterpret_cast<const float4*>(&u.qs[(grp + 16 * i) * H + (h ^ gq)]);
        #pragma unroll
        for (int j = 0; j < 5; ++j)
            ef[j] = *reinterpret_cast<const float4*>(&es[(nl + 4 * j) * H + (h ^ gej[j])]);
        #pragma unroll
        for (int i = 0; i < 8; ++i)
            #pragma unroll
            for (int j = 0; j < 5; ++j) {
                float s = sj[j];
                acc[i][j] += fabsf(fmaf(-ef[j].x, s, qf[i].x))
                           + fabsf(fmaf(-ef[j].y, s, qf[i].y))
                           + fabsf(fmaf(-ef[j].z, s, qf[i].z))
                           + fabsf(fmaf(-ef[j].w, s, qf[i].w));
            }
    }

    // ---- two-stage merge of 8 h-segment partials (aliases qs) ----
    __syncthreads();                    // all qs reads done
    if (w >= 4) {
        #pragma unroll
        for (int i = 0; i < 8; ++i)
            #pragma unroll
            for (int j = 0; j < 5; ++j)
                u.red[w - 4][grp + 16 * i][nl + 4 * j] = acc[i][j];
    }
    __syncthreads();
    if (w < 4) {
        #pragma unroll
        for (int i = 0; i < 8; ++i)
            #pragma unroll
            for (int j = 0; j < 5; ++j) {
                float v = acc[i][j] + u.red[w][grp + 16 * i][nl + 4 * j];
                u.red[w][grp + 16 * i][nl + 4 * j] = v;   // same-slot RMW, no hazard
            }
    }
    __syncthreads();

    // ---- epilogue: exp (no max: dist<=~34, f32-safe), store, psum ----
    {
        const int l  = tid >> 2;            // 0..127
        const int cg = tid & 3;             // 4 col-groups x 5
        const int n0 = cg * 5;
        float p[5];
        float rs = 0.f;
        #pragma unroll
        for (int k = 0; k < 5; ++k) {
            float d = u.red[0][l][n0 + k] + u.red[1][l][n0 + k]
                    + u.red[2][l][n0 + k] + u.red[3][l][n0 + k];
            p[k] = __expf(d);
            rs += p[k];
        }
        float* po = out + (size_t)l * N_NODES + nb + n0;
        #pragma unroll
        for (int k = 0; k < 5; ++k) po[k] = p[k];
        rs += __shfl_xor(rs, 1, 64);
        rs += __shfl_xor(rs, 2, 64);        // sums the 4 cg-lanes of this row
        if (cg == 0) psum[l * PSTR + blockIdx.x] = rs;
    }
}

// --- K2: finish softmax: per-row sum of 500 partials, scale ----------------
__global__ __launch_bounds__(256) void k_finish(float* __restrict__ out,
                                                const float* __restrict__ psum) {
    __shared__ float red[4];
    int l = blockIdx.y;
    int tid = threadIdx.x;
    const float* ps = psum + l * PSTR;
    float s = ps[tid] + (tid < NBLK - 256 ? ps[tid + 256] : 0.f);
    #pragma unroll
    for (int m = 1; m < 64; m <<= 1) s += __shfl_xor(s, m, 64);
    if ((tid & 63) == 0) red[tid >> 6] = s;
    __syncthreads();
    float inv = 1.0f / (red[0] + red[1] + red[2] + red[3]);

    int n4 = blockIdx.x * 256 + tid;           // float4 idx within row (<2500)
    if (n4 < 2500) {
        float4* o = reinterpret_cast<float4*>(out) + (size_t)l * 2500 + n4;
        float4 v = *o;
        v.x *= inv; v.y *= inv; v.z *= inv; v.w *= inv;
        *o = v;
    }
}

extern "C" void kernel_launch(void* const* d_in, const int* in_sizes, int n_in,
                              void* d_out, int out_size, void* d_ws, size_t ws_size,
                              hipStream_t stream) {
    const float* node = (const float*)d_in[0];
    const float* rel  = (const float*)d_in[1];
    const int*   eidx = (const int*)d_in[2];
    const int*   ridx = (const int*)d_in[3];
    float* out = (float*)d_out;

    float* psum = (float*)d_ws;               // 128*512 floats = 256 KB

    k_main<<<NBLK, 512, 0, stream>>>(node, rel, eidx, ridx, out, psum);

    dim3 gridC((2500 + 255) / 256, L);        // 10 x 128
    k_finish<<<gridC, 256, 0, stream>>>(out, psum);
}

// Round 21
// 25.803 us; speedup vs baseline: 1.0381x; 1.0381x over previous
//
#include <hip/hip_runtime.h>
#include <math.h>

#define N_NODES 10000
#define N_REL   500
#define H       128
#define L       128

#define TN    20     // n-tile: 500 * 20 = 10000 exactly
#define NBLK  500    // grid of k_main (2 blocks/CU)
#define PSTR  512    // psum row stride

__device__ __forceinline__ void gload16(const float* g, float* l) {
    __builtin_amdgcn_global_load_lds((const __attribute__((address_space(1))) void*)g,
                                     (__attribute__((address_space(3))) void*)l, 16, 0, 0);
}

// --- K1: per-block query rebuild + 128x20 exp(L1-dist) tile + psum ---------
// Best-known configuration (round 19, 25.75 us):
//  - es staged raw via global_load_lds w=16, pre-swizzled source
//  - redundant per-block query build (L2-hot gathers), swizzled LDS writes
//  - inverse norm folded into inner-loop fma: |q - e*s| = |fma(-e,s,q)|
//  - waves split h 4x32; lane tile 8l x 5n (minimal LDS-instr/FLOP)
//  - merge of 4 h-segment partials through aliased 43 KB buffer
//  - exp without max-subtraction (dist <= ~34, f32-safe), __expf
// LDS content swizzle: stored[row][c] = src[row][c ^ ((row&7)<<2)]
__global__ __launch_bounds__(256, 2) void k_main(const float* __restrict__ node,
                                                 const float* __restrict__ rel,
                                                 const int* __restrict__ eidx,
                                                 const int* __restrict__ ridx,
                                                 float* __restrict__ out,
                                                 float* __restrict__ psum) {
    __shared__ union {
        float qs[L * H];            // 64 KB  (build + main-loop phase)
        float red[4][128][21];      // 43 KB  (merge phase, aliases qs)
    } u;
    __shared__ float es[TN * H];    // 10 KB
    __shared__ float invs[TN];

    const int tid  = threadIdx.x;
    const int w    = tid >> 6;          // wave id = h-segment in main loop
    const int lane = tid & 63;
    const int grp  = lane >> 2;         // 0..15
    const int nl   = lane & 3;          // 0..3
    const int nb   = blockIdx.x * TN;   // exact, no bounds checks

    // ---- A1: issue es staging DMA (overlaps the query build below) ----
    {
        const int c0   = (lane & 31) << 2;
        const int roff = lane >> 5;
        #pragma unroll
        for (int k = 0; k < 10; ++k) {
            if ((k & 3) == w) {
                int r = k * 2;
                int row = r + roff;
                int g = (row & 7) << 2;
                gload16(node + (size_t)(nb + row) * H + (c0 ^ g), &es[r * H]);
            }
        }
    }

    // ---- A2: build all 128 query rows into qs (redundant per block; ----
    // ---- gathers are L2-hot: only 128KB unique data shared by all)  ----
    #pragma unroll
    for (int it = 0; it < 4; ++it) {
        int row = it * 32 + (tid >> 3);
        int seg = tid & 7;
        int ei = eidx[row], ri = ridx[row];
        const float4* pe = reinterpret_cast<const float4*>(node + (size_t)ei * H + seg * 16);
        const float4* pr = reinterpret_cast<const float4*>(rel  + (size_t)ri * H + seg * 16);
        float4 ev[4], rv[4];
        #pragma unroll
        for (int u2 = 0; u2 < 4; ++u2) { ev[u2] = pe[u2]; rv[u2] = pr[u2]; }
        float se = 0.f, sr = 0.f;
        #pragma unroll
        for (int u2 = 0; u2 < 4; ++u2) {
            se += ev[u2].x * ev[u2].x + ev[u2].y * ev[u2].y
                + ev[u2].z * ev[u2].z + ev[u2].w * ev[u2].w;
            sr += rv[u2].x * rv[u2].x + rv[u2].y * rv[u2].y
                + rv[u2].z * rv[u2].z + rv[u2].w * rv[u2].w;
        }
        se += __shfl_xor(se, 1, 64); se += __shfl_xor(se, 2, 64); se += __shfl_xor(se, 4, 64);
        sr += __shfl_xor(sr, 1, 64); sr += __shfl_xor(sr, 2, 64); sr += __shfl_xor(sr, 4, 64);
        float inve = 1.0f / fmaxf(sqrtf(se), 1e-12f);
        float invr = 1.0f / fmaxf(sqrtf(sr), 1e-12f);
        int g = (row & 7) << 2;
        float* dst = u.qs + row * H;
        #pragma unroll
        for (int u2 = 0; u2 < 4; ++u2) {
            float4 q;
            q.x = ev[u2].x * inve + rv[u2].x * invr;
            q.y = ev[u2].y * inve + rv[u2].y * invr;
            q.z = ev[u2].z * inve + rv[u2].z * invr;
            q.w = ev[u2].w * inve + rv[u2].w * invr;
            int c = (seg * 16 + u2 * 4) ^ g;        // 16B-aligned, swizzled
            *reinterpret_cast<float4*>(dst + c) = q;
        }
    }
    __syncthreads();   // drains es DMA (vmcnt) + qs LDS writes

    // ---- A3: inverse norms of the 20 es rows (swizzle-invariant) ----
    if (tid < 8 * TN) {
        int row = tid >> 3, seg = tid & 7;
        const float4* p = reinterpret_cast<const float4*>(es + row * H + seg * 16);
        float ss = 0.f;
        #pragma unroll
        for (int u2 = 0; u2 < 4; ++u2) {
            float4 v = p[u2];
            ss += v.x * v.x + v.y * v.y + v.z * v.z + v.w * v.w;
        }
        #pragma unroll
        for (int m = 1; m < 8; m <<= 1) ss += __shfl_xor(ss, m, 64);
        if (seg == 0) invs[row] = 1.0f / fmaxf(sqrtf(ss), 1e-12f);
    }
    __syncthreads();

    // ---- B: main loop, 8 h-quads; e raw from LDS, scale fused in fma ----
    const int hs = w * 32;
    const int gq = (grp & 7) << 2;
    int gej[5];
    float sj[5];
    #pragma unroll
    for (int j = 0; j < 5; ++j) {
        gej[j] = ((nl + 4 * j) & 7) << 2;
        sj[j]  = invs[nl + 4 * j];
    }

    float acc[8][5] = {};

    #pragma unroll
    for (int hc = 0; hc < 8; ++hc) {
        const int h = hs + (hc << 2);
        float4 qf[8], ef[5];
        #pragma unroll
        for (int i = 0; i < 8; ++i)
            qf[i] = *reinterpret_cast<const float4*>(&u.qs[(grp + 16 * i) * H + (h ^ gq)]);
        #pragma unroll
        for (int j = 0; j < 5; ++j)
            ef[j] = *reinterpret_cast<const float4*>(&es[(nl + 4 * j) * H + (h ^ gej[j])]);
        #pragma unroll
        for (int i = 0; i < 8; ++i)
            #pragma unroll
            for (int j = 0; j < 5; ++j) {
                float s = sj[j];
                acc[i][j] += fabsf(fmaf(-ef[j].x, s, qf[i].x))
                           + fabsf(fmaf(-ef[j].y, s, qf[i].y))
                           + fabsf(fmaf(-ef[j].z, s, qf[i].z))
                           + fabsf(fmaf(-ef[j].w, s, qf[i].w));
            }
    }

    // ---- merge 4 h-segment partials through LDS (aliases qs) ----
    __syncthreads();
    #pragma unroll
    for (int i = 0; i < 8; ++i)
        #pragma unroll
        for (int j = 0; j < 5; ++j)
            u.red[w][grp + 16 * i][nl + 4 * j] = acc[i][j];
    __syncthreads();

    // ---- epilogue: exp (no max: dist<=~34, f32-safe), store, psum ----
    {
        const int l  = tid >> 1;
        const int n0 = (tid & 1) * 10;
        float p[10];
        float rs = 0.f;
        #pragma unroll
        for (int k = 0; k < 10; ++k) {
            float d = u.red[0][l][n0 + k] + u.red[1][l][n0 + k]
                    + u.red[2][l][n0 + k] + u.red[3][l][n0 + k];
            p[k] = __expf(d);
            rs += p[k];
        }
        float* po = out + (size_t)l * N_NODES + nb + n0;
        #pragma unroll
        for (int k = 0; k < 5; ++k)
            *reinterpret_cast<float2*>(po + 2 * k) = make_float2(p[2 * k], p[2 * k + 1]);
        rs += __shfl_xor(rs, 1, 64);
        if ((tid & 1) == 0) psum[l * PSTR + blockIdx.x] = rs;
    }
}

// --- K2: finish softmax: per-row sum of 500 partials, scale ----------------
__global__ __launch_bounds__(256) void k_finish(float* __restrict__ out,
                                                const float* __restrict__ psum) {
    __shared__ float red[4];
    int l = blockIdx.y;
    int tid = threadIdx.x;
    const float* ps = psum + l * PSTR;
    float s = ps[tid] + (tid < NBLK - 256 ? ps[tid + 256] : 0.f);
    #pragma unroll
    for (int m = 1; m < 64; m <<= 1) s += __shfl_xor(s, m, 64);
    if ((tid & 63) == 0) red[tid >> 6] = s;
    __syncthreads();
    float inv = 1.0f / (red[0] + red[1] + red[2] + red[3]);

    int n4 = blockIdx.x * 256 + tid;           // float4 idx within row (<2500)
    if (n4 < 2500) {
        float4* o = reinterpret_cast<float4*>(out) + (size_t)l * 2500 + n4;
        float4 v = *o;
        v.x *= inv; v.y *= inv; v.z *= inv; v.w *= inv;
        *o = v;
    }
}

extern "C" void kernel_launch(void* const* d_in, const int* in_sizes, int n_in,
                              void* d_out, int out_size, void* d_ws, size_t ws_size,
                              hipStream_t stream) {
    const float* node = (const float*)d_in[0];
    const float* rel  = (const float*)d_in[1];
    const int*   eidx = (const int*)d_in[2];
    const int*   ridx = (const int*)d_in[3];
    float* out = (float*)d_out;

    float* psum = (float*)d_ws;               // 128*512 floats = 256 KB

    k_main<<<NBLK, 256, 0, stream>>>(node, rel, eidx, ridx, out, psum);

    dim3 gridC((2500 + 255) / 256, L);        // 10 x 128
    k_finish<<<gridC, 256, 0, stream>>>(out, psum);
}